// Round 1
// baseline (246.358 us; speedup 1.0000x reference)
//
#include <hip/hip_runtime.h>
#include <hip/hip_bf16.h>
#include <stdint.h>

#define B_   64
#define L_   4096
#define H_   128
#define T_   64
#define C_   (L_/T_)        // 64 chunks
#define BH_  (B_*H_)        // 8192
#define PADI 136            // bf16 row stride for inp / W^T tiles (16B-aligned rows)
#define PADA 130            // bf16 row stride for a/b tiles (conflict-free GEMV)

typedef __attribute__((ext_vector_type(8))) short short8;
typedef __attribute__((ext_vector_type(4))) float floatx4;

__device__ __forceinline__ unsigned short f2bf(float f){
    unsigned int u = __float_as_uint(f);
    u += 0x7FFFu + ((u >> 16) & 1u);      // round-to-nearest-even
    return (unsigned short)(u >> 16);
}
__device__ __forceinline__ float bf2f(unsigned short s){
    return __uint_as_float(((unsigned int)s) << 16);
}
__device__ __forceinline__ float sigm(float x){
    return 1.0f / (1.0f + __expf(-x));
}
__device__ __forceinline__ float tanh_f(float x){
    float xc = fminf(fmaxf(x, -20.0f), 20.0f);
    float e = __expf(-2.0f * xc);
    return (1.0f - e) / (1.0f + e);
}

// K0: W^T bf16 prep (one-time per launch; reads L2-hot, writes coalesced)
__global__ void prep_w(const float* __restrict__ Wz, const float* __restrict__ Wh,
                       unsigned short* __restrict__ WzT, unsigned short* __restrict__ WhT){
    const float* W = blockIdx.x ? Wh : Wz;
    unsigned short* WT = blockIdx.x ? WhT : WzT;
    int tid = threadIdx.x;
    for (int it = 0; it < 64; ++it){
        int idx = it*256 + tid;           // idx = n*128 + k
        int n = idx >> 7, k = idx & 127;
        WT[idx] = f2bf(W[k*H_ + n]);
    }
}

// K2: compose per-chunk aggregates into carries (h entering each chunk)
__global__ void chunk_scan(const float* __restrict__ aggA, const float* __restrict__ aggB,
                           float* __restrict__ carry){
    int tid = blockIdx.x*256 + threadIdx.x;   // 8192 = B*H
    float c = 0.0f;
    for (int ch = 0; ch < C_; ++ch){
        carry[ch*BH_ + tid] = c;
        c = fmaf(aggA[ch*BH_ + tid], c, aggB[ch*BH_ + tid]);
    }
}

// K1 (FINAL=false): GEMMs + local scan -> chunk aggregates
// K3 (FINAL=true):  GEMMs + carried scan + fused Wg readout -> preds
template<bool FINAL>
__global__ __launch_bounds__(256, 2)
void gemm_scan(const float* __restrict__ x,
               const float* __restrict__ Wp, const float* __restrict__ bp,
               const float* __restrict__ bz, const float* __restrict__ bh,
               const float* __restrict__ Wg, const float* __restrict__ bg,
               const unsigned short* __restrict__ WzT,
               const unsigned short* __restrict__ WhT,
               float* __restrict__ aggA, float* __restrict__ aggB,
               const float* __restrict__ carry,
               float* __restrict__ preds)
{
    // big region: [inp tile | W^T tile] during GEMM; [a | b] after (overlay)
    __shared__ __align__(16) unsigned short s_big[T_*PADI + H_*PADI]; // 52224 B
    unsigned short* inp_lds = s_big;                  // T_*PADI ushorts
    unsigned short* w_lds   = s_big + T_*PADI;        // H_*PADI ushorts
    unsigned short* a_lds   = s_big;                  // T_*PADA = 8320
    unsigned short* b_lds   = s_big + T_*PADA;        // ends 16640 (< 26112)
    __shared__ float s_x[T_*3];
    __shared__ float s_wp[3*H_];
    __shared__ float s_bp[H_], s_bz[H_], s_bh[H_], s_wg[H_];

    const int bid = blockIdx.x;
    const int bb  = bid / C_;
    const int cc  = bid % C_;
    const int t0  = cc * T_;
    const int tid = threadIdx.x;
    const int wv = tid >> 6, lane = tid & 63, quad = lane >> 4, l15 = lane & 15;

    // ---- stage small arrays ----
    for (int i = tid; i < 3*H_; i += 256) s_wp[i] = Wp[i];
    if (tid < T_*3) s_x[tid] = x[bb*(L_*3) + t0*3 + tid];
    if (tid < H_) { s_bp[tid]=bp[tid]; s_bz[tid]=bz[tid]; s_bh[tid]=bh[tid]; s_wg[tid]=Wg[tid]; }
    __syncthreads();

    // ---- inp = x @ Wp + bp -> bf16 LDS (A operand, row-major [t][k]) ----
    #pragma unroll
    for (int it = 0; it < 4; ++it){
        int idx = tid + it*256;           // 0..1023 chunks of 8
        int t = idx >> 4, c8 = idx & 15, h0 = c8*8;
        float x0 = s_x[t*3+0], x1 = s_x[t*3+1], x2 = s_x[t*3+2];
        short8 pk;
        #pragma unroll
        for (int m = 0; m < 8; ++m){
            int hh = h0 + m;
            float v = s_bp[hh];
            v = fmaf(x0, s_wp[hh],      v);
            v = fmaf(x1, s_wp[H_+hh],   v);
            v = fmaf(x2, s_wp[2*H_+hh], v);
            pk[m] = (short)f2bf(v);
        }
        *(short8*)&inp_lds[t*PADI + h0] = pk;
    }
    // ---- stage Wz^T ----
    #pragma unroll
    for (int it = 0; it < 8; ++it){
        int idx = tid + it*256;           // 0..2047 chunks of 8
        int n = idx >> 4, c8 = idx & 15;
        *(short8*)&w_lds[n*PADI + c8*8] = *(const short8*)&WzT[n*H_ + c8*8];
    }
    __syncthreads();

    // wave w: all 4 row-tiles (64 t-rows), col-tiles {2w, 2w+1}
    const int ct0 = wv*2;
    floatx4 accz[4][2];
    #pragma unroll
    for (int r = 0; r < 4; ++r)
        #pragma unroll
        for (int c = 0; c < 2; ++c) accz[r][c] = (floatx4){0.f,0.f,0.f,0.f};

    #pragma unroll
    for (int kk = 0; kk < 4; ++kk){
        short8 af[4], bfr[2];
        #pragma unroll
        for (int r = 0; r < 4; ++r)
            af[r] = *(const short8*)&inp_lds[(r*16 + l15)*PADI + kk*32 + quad*8];
        #pragma unroll
        for (int c = 0; c < 2; ++c)
            bfr[c] = *(const short8*)&w_lds[((ct0+c)*16 + l15)*PADI + kk*32 + quad*8];
        #pragma unroll
        for (int r = 0; r < 4; ++r)
            #pragma unroll
            for (int c = 0; c < 2; ++c)
                accz[r][c] = __builtin_amdgcn_mfma_f32_16x16x32_bf16(af[r], bfr[c], accz[r][c], 0, 0, 0);
    }
    __syncthreads();
    // ---- stage Wh^T (reuse w_lds) ----
    #pragma unroll
    for (int it = 0; it < 8; ++it){
        int idx = tid + it*256;
        int n = idx >> 4, c8 = idx & 15;
        *(short8*)&w_lds[n*PADI + c8*8] = *(const short8*)&WhT[n*H_ + c8*8];
    }
    __syncthreads();

    floatx4 acch[4][2];
    #pragma unroll
    for (int r = 0; r < 4; ++r)
        #pragma unroll
        for (int c = 0; c < 2; ++c) acch[r][c] = (floatx4){0.f,0.f,0.f,0.f};
    #pragma unroll
    for (int kk = 0; kk < 4; ++kk){
        short8 af[4], bfr[2];
        #pragma unroll
        for (int r = 0; r < 4; ++r)
            af[r] = *(const short8*)&inp_lds[(r*16 + l15)*PADI + kk*32 + quad*8];
        #pragma unroll
        for (int c = 0; c < 2; ++c)
            bfr[c] = *(const short8*)&w_lds[((ct0+c)*16 + l15)*PADI + kk*32 + quad*8];
        #pragma unroll
        for (int r = 0; r < 4; ++r)
            #pragma unroll
            for (int c = 0; c < 2; ++c)
                acch[r][c] = __builtin_amdgcn_mfma_f32_16x16x32_bf16(af[r], bfr[c], acch[r][c], 0, 0, 0);
    }
    __syncthreads();   // all waves done reading inp/w before overlay write

    // ---- epilogue: a = 1-sigmoid(Sz+bz), b = sigmoid*tanh(Sh+bh) -> bf16 LDS ----
    // C/D layout: col = lane&15, row = quad*4 + reg  (m89/m91-verified)
    #pragma unroll
    for (int r = 0; r < 4; ++r){
        #pragma unroll
        for (int c = 0; c < 2; ++c){
            int col = (ct0+c)*16 + l15;
            float vbz = s_bz[col], vbh = s_bh[col];
            #pragma unroll
            for (int e = 0; e < 4; ++e){
                int trow = r*16 + quad*4 + e;
                float z  = sigm(accz[r][c][e] + vbz);
                float ht = tanh_f(acch[r][c][e] + vbh);
                a_lds[trow*PADA + col] = f2bf(1.0f - z);
                b_lds[trow*PADA + col] = f2bf(z*ht);
            }
        }
    }
    __syncthreads();

    if (!FINAL){
        // ---- local scan -> chunk aggregate (A = prod a, B = scan from 0) ----
        if (tid < H_){
            float A = 1.0f, h = 0.0f;
            #pragma unroll 4
            for (int t = 0; t < T_; ++t){
                float aa = bf2f(a_lds[t*PADA + tid]);
                float bv = bf2f(b_lds[t*PADA + tid]);
                A *= aa;
                h = fmaf(aa, h, bv);
            }
            aggA[cc*BH_ + bb*H_ + tid] = A;
            aggB[cc*BH_ + bb*H_ + tid] = h;
        }
    } else {
        // ---- carried scan; stash h_{t-1} into b_lds rows for the readout ----
        if (tid < H_){
            float h = carry[cc*BH_ + bb*H_ + tid];
            #pragma unroll 4
            for (int t = 0; t < T_; ++t){
                float aa = bf2f(a_lds[t*PADA + tid]);
                float bv = bf2f(b_lds[t*PADA + tid]);
                b_lds[t*PADA + tid] = f2bf(h);   // h_prev for pred at this t
                h = fmaf(aa, h, bv);
            }
        }
        __syncthreads();
        // ---- fused readout: preds[t] = h_{t-1} . Wg + bg ----
        int i = tid >> 2, q = tid & 3;      // 64 rows x 4-thread dot
        float s = 0.0f;
        #pragma unroll 8
        for (int jj = 0; jj < 32; ++jj){
            int col = q*32 + jj;
            s = fmaf(bf2f(b_lds[i*PADA + col]), s_wg[col], s);
        }
        s += __shfl_xor(s, 1, 64);
        s += __shfl_xor(s, 2, 64);
        if (q == 0) preds[bb*L_ + t0 + i] = s + bg[0];
    }
}

extern "C" void kernel_launch(void* const* d_in, const int* in_sizes, int n_in,
                              void* d_out, int out_size, void* d_ws, size_t ws_size,
                              hipStream_t stream){
    const float* x  = (const float*)d_in[0];
    const float* Wp = (const float*)d_in[1];
    const float* bp = (const float*)d_in[2];
    const float* Wz = (const float*)d_in[3];
    const float* bz = (const float*)d_in[4];
    const float* Wh = (const float*)d_in[5];
    const float* bh = (const float*)d_in[6];
    const float* Wg = (const float*)d_in[7];
    const float* bg = (const float*)d_in[8];
    float* preds = (float*)d_out;

    uint8_t* w8 = (uint8_t*)d_ws;
    unsigned short* WzT = (unsigned short*)(w8);
    unsigned short* WhT = (unsigned short*)(w8 + 32768);
    float* aggA  = (float*)(w8 + 65536);
    float* aggB  = (float*)(w8 + 65536 + 4u*BH_*C_);
    float* carry = (float*)(w8 + 65536 + 8u*BH_*C_);

    hipLaunchKernelGGL(prep_w, dim3(2), dim3(256), 0, stream, Wz, Wh, WzT, WhT);
    hipLaunchKernelGGL(HIP_KERNEL_NAME(gemm_scan<false>), dim3(B_*C_), dim3(256), 0, stream,
                       x, Wp, bp, bz, bh, Wg, bg, WzT, WhT,
                       aggA, aggB, (const float*)nullptr, (float*)nullptr);
    hipLaunchKernelGGL(chunk_scan, dim3(BH_/256), dim3(256), 0, stream, aggA, aggB, carry);
    hipLaunchKernelGGL(HIP_KERNEL_NAME(gemm_scan<true>), dim3(B_*C_), dim3(256), 0, stream,
                       x, Wp, bp, bz, bh, Wg, bg, WzT, WhT,
                       (float*)nullptr, (float*)nullptr, carry, preds);
}

// Round 2
// 186.541 us; speedup vs baseline: 1.3207x; 1.3207x over previous
//
#include <hip/hip_runtime.h>
#include <hip/hip_bf16.h>
#include <stdint.h>

#define B_   64
#define L_   4096
#define H_   128
#define T_   64
#define C_   (L_/T_)        // 64 chunks
#define BH_  (B_*H_)        // 8192
#define PADI 136            // bf16 row stride for inp tile (16B-aligned rows, conflict-balanced)
#define PAB  136            // ushorts per col-row of interleaved (a,b) pairs: 64*2 + 8 pad

typedef __attribute__((ext_vector_type(8))) short short8;
typedef __attribute__((ext_vector_type(4))) float floatx4;

#define LOG2E 1.44269504088896340736f

__device__ __forceinline__ unsigned short f2bf(float f){
    unsigned int u = __float_as_uint(f);
    u += 0x7FFFu + ((u >> 16) & 1u);      // RNE
    return (unsigned short)(u >> 16);
}
__device__ __forceinline__ float bf2f(unsigned short s){
    return __uint_as_float(((unsigned int)s) << 16);
}

// K0: W^T bf16 prep with per-row XOR swizzle of 16B k-chunks.
// Element (n,k) -> WT[n*128 + ((k>>3)^(n&7))*8 + (k&7)], so the dense LDS copy
// gives conflict-free B-fragment ds_read_b128 (banks 4*((kc^(l15&7))..) balanced).
__global__ void prep_w(const float* __restrict__ Wz, const float* __restrict__ Wh,
                       unsigned short* __restrict__ WzT, unsigned short* __restrict__ WhT){
    const float* W = blockIdx.x ? Wh : Wz;
    unsigned short* WT = blockIdx.x ? WhT : WzT;
    int tid = threadIdx.x;
    for (int it = 0; it < 64; ++it){
        int idx = it*256 + tid;           // idx = n*128 + k
        int n = idx >> 7, k = idx & 127;
        int dst = n*128 + (((k >> 3) ^ (n & 7)) << 3) + (k & 7);
        WT[dst] = f2bf(W[k*H_ + n]);
    }
}

// K2: compose per-chunk aggregates into carries (h entering each chunk)
__global__ void chunk_scan(const float* __restrict__ aggA, const float* __restrict__ aggB,
                           float* __restrict__ carry){
    int tid = blockIdx.x*256 + threadIdx.x;   // 8192 = B*H
    float c = 0.0f;
    #pragma unroll 8
    for (int ch = 0; ch < C_; ++ch){
        carry[ch*BH_ + tid] = c;
        c = fmaf(aggA[ch*BH_ + tid], c, aggB[ch*BH_ + tid]);
    }
}

// K1 (FINAL=false): inp + 2 GEMMs + gates + local scan -> chunk aggregates
// K3 (FINAL=true):  same + carried scan + fused Wg readout -> preds
template<bool FINAL>
__global__ __launch_bounds__(256, 3)
void gemm_scan(const float* __restrict__ x,
               const float* __restrict__ Wp, const float* __restrict__ bp,
               const float* __restrict__ bz, const float* __restrict__ bh,
               const float* __restrict__ Wg, const float* __restrict__ bg,
               const unsigned short* __restrict__ WzT,
               const unsigned short* __restrict__ WhT,
               float* __restrict__ aggA, float* __restrict__ aggB,
               const float* __restrict__ carry,
               float* __restrict__ preds)
{
    // [inp 64x136 | W 128x128 dense] = 50176 B; (a,b) pairs overlay from 0.
    __shared__ __align__(16) unsigned short s_big[T_*PADI + H_*H_];
    __shared__ float s_bz[H_], s_bh[H_], s_wg[H_];
    unsigned short* inp_lds = s_big;                 // 8704 ushorts
    unsigned short* w_lds   = s_big + T_*PADI;       // 16384 ushorts (dense, swizzled)
    unsigned short* ab_lds  = s_big;                 // overlay: 128 cols x 136 = 17408

    const int bid = blockIdx.x;
    const int bb  = bid / C_;
    const int cc  = bid % C_;
    const int t0g = cc * T_;
    const int tid = threadIdx.x;
    const int wv = tid >> 6, lane = tid & 63, quad = lane >> 4, l15 = lane & 15;

    // ---- phase 0: async Wz -> LDS (16B/lane direct-to-LDS), biases, inp compute ----
    {
        const char* wsrc = (const char*)WzT;
        char* wdst = (char*)w_lds;
        #pragma unroll
        for (int i = 0; i < 8; ++i){
            int off = (wv*8 + i)*1024;
            __builtin_amdgcn_global_load_lds(
                (const __attribute__((address_space(1))) unsigned int*)(wsrc + off + lane*16),
                (__attribute__((address_space(3))) unsigned int*)(wdst + off), 16, 0, 0);
        }
    }
    if (tid < H_){ s_bz[tid] = bz[tid]; s_bh[tid] = bh[tid]; s_wg[tid] = Wg[tid]; }

    // inp = x @ Wp + bp -> bf16 LDS (A layout [t][k], PADI rows). Wp/bp/x L1/L2-hot.
    #pragma unroll
    for (int it = 0; it < 4; ++it){
        int idx = tid + it*256;
        int t = idx >> 4, h0 = (idx & 15) * 8;
        const float* xr = x + ((size_t)bb*L_ + t0g + t)*3;
        float x0 = xr[0], x1 = xr[1], x2 = xr[2];
        short8 pk;
        #pragma unroll
        for (int m = 0; m < 8; ++m){
            int hh = h0 + m;
            float v = bp[hh];
            v = fmaf(x0, Wp[hh],      v);
            v = fmaf(x1, Wp[H_+hh],   v);
            v = fmaf(x2, Wp[2*H_+hh], v);
            pk[m] = (short)f2bf(v);
        }
        *(short8*)&inp_lds[t*PADI + h0] = pk;
    }
    __syncthreads();

    // ---- GEMM1: Sz = inp @ Wz^T ----
    const int ct0 = wv*2;
    floatx4 accz[4][2];
    #pragma unroll
    for (int r = 0; r < 4; ++r)
        #pragma unroll
        for (int c = 0; c < 2; ++c) accz[r][c] = (floatx4){0.f,0.f,0.f,0.f};

    #pragma unroll
    for (int kk = 0; kk < 4; ++kk){
        short8 af[4], bfr[2];
        #pragma unroll
        for (int r = 0; r < 4; ++r)
            af[r] = *(const short8*)&inp_lds[(r*16 + l15)*PADI + kk*32 + quad*8];
        const int kcs = (((kk*4 + quad) ^ (l15 & 7)) << 3);
        #pragma unroll
        for (int c = 0; c < 2; ++c)
            bfr[c] = *(const short8*)&w_lds[((ct0+c)*16 + l15)*H_ + kcs];
        #pragma unroll
        for (int r = 0; r < 4; ++r)
            #pragma unroll
            for (int c = 0; c < 2; ++c)
                accz[r][c] = __builtin_amdgcn_mfma_f32_16x16x32_bf16(af[r], bfr[c], accz[r][c], 0, 0, 0);
    }

    // a = 1 - sigmoid(sz) = 1/(1+exp2(log2e*sz)); quantize to bf16 now, keep packed.
    unsigned int a2[4][2][2];
    #pragma unroll
    for (int r = 0; r < 4; ++r){
        #pragma unroll
        for (int c = 0; c < 2; ++c){
            int col = (ct0+c)*16 + l15;
            float vbz = s_bz[col];
            unsigned short q[4];
            #pragma unroll
            for (int e = 0; e < 4; ++e){
                float szb = accz[r][c][e] + vbz;
                float a = __builtin_amdgcn_rcpf(1.0f + __builtin_amdgcn_exp2f(szb * LOG2E));
                q[e] = f2bf(a);
            }
            a2[r][c][0] = (unsigned int)q[0] | ((unsigned int)q[1] << 16);
            a2[r][c][1] = (unsigned int)q[2] | ((unsigned int)q[3] << 16);
        }
    }
    __syncthreads();   // all waves done reading Wz before overwrite

    // ---- async Wh -> LDS ----
    {
        const char* wsrc = (const char*)WhT;
        char* wdst = (char*)w_lds;
        #pragma unroll
        for (int i = 0; i < 8; ++i){
            int off = (wv*8 + i)*1024;
            __builtin_amdgcn_global_load_lds(
                (const __attribute__((address_space(1))) unsigned int*)(wsrc + off + lane*16),
                (__attribute__((address_space(3))) unsigned int*)(wdst + off), 16, 0, 0);
        }
    }
    __syncthreads();

    // ---- GEMM2: Sh = inp @ Wh^T ----
    floatx4 acch[4][2];
    #pragma unroll
    for (int r = 0; r < 4; ++r)
        #pragma unroll
        for (int c = 0; c < 2; ++c) acch[r][c] = (floatx4){0.f,0.f,0.f,0.f};
    #pragma unroll
    for (int kk = 0; kk < 4; ++kk){
        short8 af[4], bfr[2];
        #pragma unroll
        for (int r = 0; r < 4; ++r)
            af[r] = *(const short8*)&inp_lds[(r*16 + l15)*PADI + kk*32 + quad*8];
        const int kcs = (((kk*4 + quad) ^ (l15 & 7)) << 3);
        #pragma unroll
        for (int c = 0; c < 2; ++c)
            bfr[c] = *(const short8*)&w_lds[((ct0+c)*16 + l15)*H_ + kcs];
        #pragma unroll
        for (int r = 0; r < 4; ++r)
            #pragma unroll
            for (int c = 0; c < 2; ++c)
                acch[r][c] = __builtin_amdgcn_mfma_f32_16x16x32_bf16(af[r], bfr[c], acch[r][c], 0, 0, 0);
    }
    __syncthreads();   // all waves done reading inp/Wh before ab overlay

    // ---- epilogue: b = (1-a)*tanh(sh); write interleaved (a,b) pairs, b128 each ----
    // C/D layout: col = lane&15 (+16*coltile), row = quad*4 + e
    #pragma unroll
    for (int r = 0; r < 4; ++r){
        #pragma unroll
        for (int c = 0; c < 2; ++c){
            int col = (ct0+c)*16 + l15;
            float vbh = s_bh[col];
            short8 pk;
            #pragma unroll
            for (int e = 0; e < 4; ++e){
                unsigned short abf = (unsigned short)(a2[r][c][e>>1] >> ((e & 1)*16));
                float a = bf2f(abf);
                float z = 1.0f - a;
                float shb = acch[r][c][e] + vbh;
                float e2 = __builtin_amdgcn_exp2f(2.0f*LOG2E*fabsf(shb));
                float tt = 1.0f - 2.0f*__builtin_amdgcn_rcpf(e2 + 1.0f);
                float bt = z * copysignf(tt, shb);
                pk[2*e]   = (short)abf;
                pk[2*e+1] = (short)f2bf(bt);
            }
            int t0l = r*16 + quad*4;
            *(short8*)&ab_lds[col*PAB + 2*t0l] = pk;
        }
    }
    __syncthreads();

    if (!FINAL){
        // ---- local scan -> chunk aggregate (A = prod a, B = scan from 0) ----
        if (tid < H_){
            float A = 1.0f, h = 0.0f;
            #pragma unroll
            for (int tt4 = 0; tt4 < 16; ++tt4){
                short8 pr = *(const short8*)&ab_lds[tid*PAB + tt4*8];
                #pragma unroll
                for (int e = 0; e < 4; ++e){
                    float aa = bf2f((unsigned short)pr[2*e]);
                    float bv = bf2f((unsigned short)pr[2*e+1]);
                    A *= aa;
                    h = fmaf(aa, h, bv);
                }
            }
            aggA[cc*BH_ + bb*H_ + tid] = A;
            aggB[cc*BH_ + bb*H_ + tid] = h;
        }
    } else {
        // ---- carried scan; overwrite a-slots with h_prev*wg for the readout ----
        if (tid < H_){
            float h = carry[cc*BH_ + bb*H_ + tid];
            float wgv = s_wg[tid];
            #pragma unroll
            for (int tt4 = 0; tt4 < 16; ++tt4){
                short8 pr = *(const short8*)&ab_lds[tid*PAB + tt4*8];
                #pragma unroll
                for (int e = 0; e < 4; ++e){
                    float aa = bf2f((unsigned short)pr[2*e]);
                    float bv = bf2f((unsigned short)pr[2*e+1]);
                    ab_lds[tid*PAB + 2*(tt4*4 + e)] = f2bf(h * wgv);
                    h = fmaf(aa, h, bv);
                }
            }
        }
        __syncthreads();
        // ---- readout: preds[t] = sum_col hw[col][t] + bg ----
        if (tid < H_){
            int t = tid >> 1, half = tid & 1;
            float s = 0.0f;
            #pragma unroll 16
            for (int j = 0; j < 64; ++j){
                int col = half*64 + j;
                s += bf2f(ab_lds[col*PAB + 2*t]);
            }
            s += __shfl_xor(s, 1, 64);
            if (half == 0) preds[(size_t)bb*L_ + t0g + t] = s + bg[0];
        }
    }
}

extern "C" void kernel_launch(void* const* d_in, const int* in_sizes, int n_in,
                              void* d_out, int out_size, void* d_ws, size_t ws_size,
                              hipStream_t stream){
    const float* x  = (const float*)d_in[0];
    const float* Wp = (const float*)d_in[1];
    const float* bp = (const float*)d_in[2];
    const float* Wz = (const float*)d_in[3];
    const float* bz = (const float*)d_in[4];
    const float* Wh = (const float*)d_in[5];
    const float* bh = (const float*)d_in[6];
    const float* Wg = (const float*)d_in[7];
    const float* bg = (const float*)d_in[8];
    float* preds = (float*)d_out;

    uint8_t* w8 = (uint8_t*)d_ws;
    unsigned short* WzT = (unsigned short*)(w8);
    unsigned short* WhT = (unsigned short*)(w8 + 32768);
    float* aggA  = (float*)(w8 + 65536);
    float* aggB  = (float*)(w8 + 65536 + 4u*BH_*C_);
    float* carry = (float*)(w8 + 65536 + 8u*BH_*C_);

    hipLaunchKernelGGL(prep_w, dim3(2), dim3(256), 0, stream, Wz, Wh, WzT, WhT);
    hipLaunchKernelGGL(HIP_KERNEL_NAME(gemm_scan<false>), dim3(B_*C_), dim3(256), 0, stream,
                       x, Wp, bp, bz, bh, Wg, bg, WzT, WhT,
                       aggA, aggB, (const float*)nullptr, (float*)nullptr);
    hipLaunchKernelGGL(chunk_scan, dim3(BH_/256), dim3(256), 0, stream, aggA, aggB, carry);
    hipLaunchKernelGGL(HIP_KERNEL_NAME(gemm_scan<true>), dim3(B_*C_), dim3(256), 0, stream,
                       x, Wp, bp, bz, bh, Wg, bg, WzT, WhT,
                       (float*)nullptr, (float*)nullptr, carry, preds);
}